// Round 1
// baseline (443.885 us; speedup 1.0000x reference)
//
#include <hip/hip_runtime.h>

// PiecewiseLinearEmbedding: out[i,t,:] = cumsum(W, axis=1)[:, x[i,t]] + b
//   x: (8192,200) int32 in [0,128]   W: (64,129) fp32   b: (64,) fp32
//   out: (8192,200,64) fp32 = 419.4 MB  -> pure streaming-write bound.

constexpr int F1     = 129;             // NUM_FEATURE + 1 bins
constexpr int D      = 64;              // VECTOR_DIM
constexpr int ROWS   = 8192 * 200;      // 1,638,400 lookup rows
constexpr int TOTAL4 = ROWS * D / 4;    // 26,214,400 float4 outputs
constexpr int TBL_F  = F1 * D;          // 8,256 floats (33,024 B) table
constexpr int TBL4   = TBL_F / 4;       // 2,064 float4

// 1024 persistent blocks (4 blocks/CU — exactly the 160KiB/33KB LDS limit),
// constant trip count: 26,214,400 / (1024*256) = 100 iterations per thread.
// This keeps table->LDS staging to 1024 copies (34 MB total) instead of ~100k.
constexpr int BLOCKS = 1024;
constexpr int TPB    = 256;
constexpr int ITERS  = TOTAL4 / (BLOCKS * TPB);   // == 100 exactly

typedef float floatx4 __attribute__((ext_vector_type(4)));

// Kernel 1: table[j*64+d] = sum_{k<=j} W[d,k] + b[d].  Tiny (one wave).
__global__ void build_table_kernel(const float* __restrict__ W,
                                   const float* __restrict__ b,
                                   float* __restrict__ tbl) {
    int d = threadIdx.x;
    if (d >= D) return;
    float bias = b[d];
    float acc = 0.0f;
    for (int j = 0; j < F1; ++j) {
        acc += W[d * F1 + j];
        tbl[j * D + d] = acc + bias;
    }
}

// Kernel 2: stage table to LDS, then gather+stream out.
// Lane -> one float4 of output: row = gid>>4, quad = gid&15.
__global__ __launch_bounds__(TPB) void embed_main_kernel(
        const int* __restrict__ x,
        const float* __restrict__ tbl,
        float* __restrict__ out) {
    __shared__ floatx4 lds_tbl[TBL4];
    const floatx4* t4 = (const floatx4*)tbl;
    for (int i = threadIdx.x; i < TBL4; i += TPB)
        lds_tbl[i] = t4[i];
    __syncthreads();

    floatx4* out4 = (floatx4*)out;
    const int base = blockIdx.x * TPB + threadIdx.x;
#pragma unroll 4
    for (int it = 0; it < ITERS; ++it) {
        int gid  = it * (BLOCKS * TPB) + base;
        int row  = gid >> 4;           // which (i,t) lookup row
        int quad = gid & 15;           // which float4 within the 64-vector
        int xi   = x[row];             // 16 lanes share this load (one line)
        floatx4 v = lds_tbl[xi * 16 + quad];
        // Output is write-once and >> L2: non-temporal streaming store.
        __builtin_nontemporal_store(v, &out4[gid]);
    }
}

extern "C" void kernel_launch(void* const* d_in, const int* in_sizes, int n_in,
                              void* d_out, int out_size, void* d_ws, size_t ws_size,
                              hipStream_t stream) {
    const int*   x = (const int*)  d_in[0];
    const float* W = (const float*)d_in[1];
    const float* b = (const float*)d_in[2];
    float* out = (float*)d_out;
    float* tbl = (float*)d_ws;     // 33,024 B scratch; rebuilt every call

    build_table_kernel<<<1, 64, 0, stream>>>(W, b, tbl);
    embed_main_kernel<<<BLOCKS, TPB, 0, stream>>>(x, tbl, out);
}

// Round 2
// 427.767 us; speedup vs baseline: 1.0377x; 1.0377x over previous
//
#include <hip/hip_runtime.h>

// PiecewiseLinearEmbedding: out[i,t,:] = cumsum(W, axis=1)[:, x[i,t]] + b
//   x: (8192,200) int32 in [0,128]   W: (64,129) fp32   b: (64,) fp32
//   out: (8192,200,64) fp32 = 419.4 MB  -> pure streaming-write bound.
// R2: parallel table build (coalesced), x staged to LDS per block (no global
// loads in hot loop), plain stores (the 6.4 TB/s harness fill uses plain).

constexpr int F1   = 129;              // NUM_FEATURE + 1 bins
constexpr int D    = 64;               // VECTOR_DIM
constexpr int ROWS = 8192 * 200;       // 1,638,400 lookup rows
constexpr int TBL_F = F1 * D;          // 8,256 floats (33,024 B)
constexpr int TBL4  = TBL_F / 4;       // 2,064 float4

constexpr int BLOCKS = 1024;           // 4 blocks/CU (LDS-limited: 39.4 KB each)
constexpr int TPB    = 256;
constexpr int ROWS_PER_BLOCK = ROWS / BLOCKS;          // 1600
constexpr int Q_PER_BLOCK    = ROWS_PER_BLOCK * D / 4; // 25,600 float4
constexpr int ITERS          = Q_PER_BLOCK / TPB;      // 100 exactly

typedef float floatx4 __attribute__((ext_vector_type(4)));

// Kernel 1: tbl[j*64+d] = b[d] + sum_{k<=j} W[d,k].
// W staged to LDS coalesced; wave 0 scans; stores are coalesced (64 lanes ->
// contiguous 256 B per j). ~129 LDS-read+add+store iterations, a few us.
__global__ __launch_bounds__(TPB) void build_table_kernel(
        const float* __restrict__ W,
        const float* __restrict__ b,
        float* __restrict__ tbl) {
    __shared__ float ldsW[TBL_F];
    for (int i = threadIdx.x; i < TBL_F; i += TPB)
        ldsW[i] = W[i];
    __syncthreads();
    int d = threadIdx.x;
    if (d < D) {
        float acc = b[d];
        // LDS read bank: (d*129+j)%32 = (d+j)%32 -> 2 lanes/bank (free).
        for (int j = 0; j < F1; ++j) {
            acc += ldsW[d * F1 + j];
            tbl[j * D + d] = acc;
        }
    }
}

// Kernel 2: per block, stage table (33 KB) + this block's 1600 x values
// (6.4 KB) into LDS, then 100 iterations of LDS-gather -> coalesced
// 16 B/lane streaming stores. No global loads in the hot loop.
__global__ __launch_bounds__(TPB) void embed_main_kernel(
        const int* __restrict__ x,
        const float* __restrict__ tbl,
        float* __restrict__ out) {
    __shared__ floatx4 lds_tbl[TBL4];          // 33,024 B
    __shared__ int     lds_x[ROWS_PER_BLOCK];  //  6,400 B  (total 39,424 B)

    const floatx4* t4 = (const floatx4*)tbl;
    for (int i = threadIdx.x; i < TBL4; i += TPB)
        lds_tbl[i] = t4[i];
    const int row0 = blockIdx.x * ROWS_PER_BLOCK;
    for (int i = threadIdx.x; i < ROWS_PER_BLOCK; i += TPB)
        lds_x[i] = x[row0 + i];
    __syncthreads();

    floatx4* out4 = (floatx4*)out + (size_t)blockIdx.x * Q_PER_BLOCK;
#pragma unroll 4
    for (int it = 0; it < ITERS; ++it) {
        int j    = it * TPB + threadIdx.x;   // block-local float4 index
        int xi   = lds_x[j >> 4];            // broadcast read (16 lanes/addr)
        floatx4 v = lds_tbl[xi * 16 + (j & 15)];  // 256B run, 2-way bank (free)
        out4[j] = v;                         // wave: 1 KB contiguous store
    }
}

extern "C" void kernel_launch(void* const* d_in, const int* in_sizes, int n_in,
                              void* d_out, int out_size, void* d_ws, size_t ws_size,
                              hipStream_t stream) {
    const int*   x = (const int*)  d_in[0];
    const float* W = (const float*)d_in[1];
    const float* b = (const float*)d_in[2];
    float* out = (float*)d_out;
    float* tbl = (float*)d_ws;     // 33,024 B scratch; rebuilt every call

    build_table_kernel<<<1, TPB, 0, stream>>>(W, b, tbl);
    embed_main_kernel<<<BLOCKS, TPB, 0, stream>>>(x, tbl, out);
}

// Round 4
// 422.044 us; speedup vs baseline: 1.0517x; 1.0136x over previous
//
#include <hip/hip_runtime.h>

// PiecewiseLinearEmbedding: out[i,t,:] = cumsum(W, axis=1)[:, x[i,t]] + b
//   x: (8192,200) int32 in [0,128]   W: (64,129) fp32   b: (64,) fp32
//   out: (8192,200,64) fp32 = 419.4 MB  -> pure streaming-write bound.
// R4 == R3 (resubmit; R3 hit GPUAcquisitionTimeout, no data).
// R3: occupancy fix. TPB 256 -> 512 with the same 39.4 KB LDS/block keeps
// 4 blocks/CU (157.7 KB <= 160 KB) but doubles waves/CU to 32 (100%).
// Streaming-store kernels need max outstanding stores; the harness's own
// 6.2 TB/s fill runs at 32 waves/CU, ours ran at 16.

constexpr int F1   = 129;              // NUM_FEATURE + 1 bins
constexpr int D    = 64;               // VECTOR_DIM
constexpr int ROWS = 8192 * 200;       // 1,638,400 lookup rows
constexpr int TBL_F = F1 * D;          // 8,256 floats (33,024 B)
constexpr int TBL4  = TBL_F / 4;       // 2,064 float4

constexpr int BLOCKS = 1024;
constexpr int TPB    = 512;            // 4 blocks/CU -> 32 waves/CU (100%)
constexpr int ROWS_PER_BLOCK = ROWS / BLOCKS;          // 1600
constexpr int Q_PER_BLOCK    = ROWS_PER_BLOCK * D / 4; // 25,600 float4
constexpr int ITERS          = Q_PER_BLOCK / TPB;      // 50 exactly

typedef float floatx4 __attribute__((ext_vector_type(4)));

// Kernel 1: tbl[j*64+d] = b[d] + sum_{k<=j} W[d,k].
// W staged to LDS coalesced; 64 lanes scan; stores coalesced (256 B per j).
__global__ __launch_bounds__(256) void build_table_kernel(
        const float* __restrict__ W,
        const float* __restrict__ b,
        float* __restrict__ tbl) {
    __shared__ float ldsW[TBL_F];
    for (int i = threadIdx.x; i < TBL_F; i += 256)
        ldsW[i] = W[i];
    __syncthreads();
    int d = threadIdx.x;
    if (d < D) {
        float acc = b[d];
        for (int j = 0; j < F1; ++j) {
            acc += ldsW[d * F1 + j];     // bank (d+j)%32: 2-way, free
            tbl[j * D + d] = acc;        // coalesced 256 B store
        }
    }
}

// Kernel 2: stage table (33 KB) + block's 1600 x values (6.4 KB) into LDS,
// then 50 iterations of LDS-gather -> coalesced 16 B/lane streaming stores.
// Hot loop is lgkm-only; stores are fire-and-forget.
__global__ __launch_bounds__(TPB, 8) void embed_main_kernel(
        const int* __restrict__ x,
        const float* __restrict__ tbl,
        float* __restrict__ out) {
    __shared__ floatx4 lds_tbl[TBL4];          // 33,024 B
    __shared__ int     lds_x[ROWS_PER_BLOCK];  //  6,400 B  (39,424 B total)

    const floatx4* t4 = (const floatx4*)tbl;
    for (int i = threadIdx.x; i < TBL4; i += TPB)
        lds_tbl[i] = t4[i];
    const int row0 = blockIdx.x * ROWS_PER_BLOCK;
    for (int i = threadIdx.x; i < ROWS_PER_BLOCK; i += TPB)
        lds_x[i] = x[row0 + i];
    __syncthreads();

    floatx4* out4 = (floatx4*)out + (size_t)blockIdx.x * Q_PER_BLOCK;
#pragma unroll 5
    for (int it = 0; it < ITERS; ++it) {
        int j    = it * TPB + threadIdx.x;   // block-local float4 index
        int xi   = lds_x[j >> 4];            // broadcast (16 lanes/addr)
        // word addr = xi*64 + quad*4 (+w); xi*64 % 32 == 0 -> every bank hit
        // exactly 8x per wave b128: uniform, conflict-free.
        floatx4 v = lds_tbl[xi * 16 + (j & 15)];
        out4[j] = v;                         // wave: 1 KB contiguous store
    }
}

extern "C" void kernel_launch(void* const* d_in, const int* in_sizes, int n_in,
                              void* d_out, int out_size, void* d_ws, size_t ws_size,
                              hipStream_t stream) {
    const int*   x = (const int*)  d_in[0];
    const float* W = (const float*)d_in[1];
    const float* b = (const float*)d_in[2];
    float* out = (float*)d_out;
    float* tbl = (float*)d_ws;     // 33,024 B scratch; rebuilt every call

    build_table_kernel<<<1, 256, 0, stream>>>(W, b, tbl);
    embed_main_kernel<<<BLOCKS, TPB, 0, stream>>>(x, tbl, out);
}